// Round 2
// baseline (2796.371 us; speedup 1.0000x reference)
//
#include <hip/hip_runtime.h>
#include <cstdint>
#include <cstddef>

#define B64 64
#define TDEC 20
#define VV 12000
#define EE 256
#define HH 512
#define DD 1024
#define RR 36

// ---------------- sort (stable argsort desc by length) ----------------
__global__ void k_sort(const int* __restrict__ cap_len,
                       const int* __restrict__ captions,
                       int* __restrict__ sind, int* __restrict__ dec_i,
                       int* __restrict__ caps_s,
                       float* __restrict__ out_dec,
                       float* __restrict__ out_sind,
                       float* __restrict__ out_caps)
{
    int i = threadIdx.x;
    __shared__ int lens[B64];
    lens[i] = cap_len[i];
    __syncthreads();
    int li = lens[i];
    int rank = 0;
    for (int j = 0; j < B64; ++j) {
        int lj = lens[j];
        if (lj > li || (lj == li && j < i)) rank++;
    }
    sind[rank] = i;
    dec_i[rank] = li - 1;
    out_dec[rank] = (float)(li - 1);
    out_sind[rank] = (float)i;
    for (int t = 0; t < 21; ++t) {
        int tok = captions[i * 21 + t];
        caps_s[rank * 21 + t] = tok;
        if (t >= 1) out_caps[rank * 20 + (t - 1)] = (float)tok;
    }
}

// ---------------- init h/c/rf (yT layout: [k][b], k in [0,1024)=rf, [1024,1536)=h) ----
__global__ void k_init(const float* __restrict__ h0, const int* __restrict__ sind,
                       float* __restrict__ yT, float* __restrict__ cT)
{
    int idx = blockIdx.x * blockDim.x + threadIdx.x;
    const int total = DD * B64 + HH * B64;
    for (; idx < total; idx += gridDim.x * blockDim.x) {
        if (idx < DD * B64) {
            yT[idx] = 0.0f;
        } else {
            int j = idx - DD * B64;   // k*64+b
            int k = j >> 6, b = j & 63;
            float v = h0[sind[b] * HH + k];
            yT[DD * B64 + j] = v;
            cT[j] = v;
        }
    }
}

// ---------------- gather sorted object proposals ----------------
__global__ void k_gobjs(const float* __restrict__ objs, const int* __restrict__ sind,
                        float* __restrict__ objs_s)
{
    size_t idx = (size_t)blockIdx.x * blockDim.x + threadIdx.x;
    const size_t total = (size_t)B64 * RR * DD;
    const size_t stride = (size_t)gridDim.x * blockDim.x;
    for (; idx < total; idx += stride) {
        int b = (int)(idx / (RR * DD));
        int rest = (int)(idx % (RR * DD));
        objs_s[idx] = objs[(size_t)sind[b] * (RR * DD) + rest];
    }
}

// ---------------- gather embeddings for all (t,b) ----------------
__global__ void k_gA(const float* __restrict__ embW, const int* __restrict__ caps_s,
                     float* __restrict__ Aemb)
{
    int idx = blockIdx.x * blockDim.x + threadIdx.x;
    if (idx >= TDEC * B64 * EE) return;
    int tb = idx >> 8, e = idx & 255;
    int t = tb >> 6, b = tb & 63;
    int tok = caps_s[b * 21 + t];
    Aemb[idx] = embW[(size_t)tok * EE + e];
}

// ---------------- emb_sum partials + reduce ----------------
__global__ void k_embsum(const float* __restrict__ embW, float* __restrict__ partial)
{
    int e = threadIdx.x;
    int v0 = blockIdx.x * 188;
    int v1 = v0 + 188; if (v1 > VV) v1 = VV;
    float a = 0.0f;
    for (int v = v0; v < v1; ++v) a += embW[(size_t)v * EE + e];
    partial[blockIdx.x * EE + e] = a;
}
__global__ void k_embred(const float* __restrict__ partial, float* __restrict__ emb_sum)
{
    int e = threadIdx.x;
    float a = 0.0f;
    for (int j = 0; j < 64; ++j) a += partial[j * EE + e];
    emb_sum[e] = a;
}

// ---------------- pw_sum_d[d] = emb_sum . wr_W[d,:] + V*wr_b[d] ----------------
__global__ void k_pwsum(const float* __restrict__ emb_sum, const float* __restrict__ wrW,
                        const float* __restrict__ wr_b, float* __restrict__ pw)
{
    __shared__ float es[EE];
    es[threadIdx.x] = emb_sum[threadIdx.x];
    __syncthreads();
    int d = blockIdx.x * 256 + threadIdx.x;
    float a = 0.0f;
    const float* row = wrW + (size_t)d * EE;
    for (int e = 0; e < EE; ++e) a = fmaf(es[e], row[e], a);
    pw[d] = a + 12000.0f * wr_b[d];
}

// ---------------- per-b: obj_sum -> s_wr, srb, sumv_wr, r_lin ----------------
__global__ void k_objpre(const float* __restrict__ objs_s, const float* __restrict__ wrW,
                         const float* __restrict__ wr_b, const float* __restrict__ pw,
                         const float* __restrict__ rW, const float* __restrict__ r_b,
                         float* __restrict__ s_wr, float* __restrict__ srb,
                         float* __restrict__ sumv, float* __restrict__ r_lin)
{
    int b = blockIdx.x, tid = threadIdx.x;
    __shared__ float os[DD];
    __shared__ float red[256];
    const float* ob = objs_s + (size_t)b * RR * DD;
    for (int d = tid; d < DD; d += 256) {
        float a = 0.0f;
        for (int r = 0; r < RR; ++r) a += ob[r * DD + d];
        os[d] = a;
    }
    __syncthreads();
    // s_wr[b][e]
    float a = 0.0f;
    for (int d = 0; d < DD; ++d) a = fmaf(os[d], wrW[(size_t)d * EE + tid], a);
    s_wr[b * EE + tid] = a;
    // srb[b]
    float p = 0.0f;
    for (int d = tid; d < DD; d += 256) p = fmaf(os[d], wr_b[d], p);
    red[tid] = p;
    __syncthreads();
    for (int s = 128; s > 0; s >>= 1) { if (tid < s) red[tid] += red[tid + s]; __syncthreads(); }
    if (tid == 0) srb[b] = red[0];
    // sumv_wr, r_lin
    if (tid < RR) {
        const float* row = ob + (size_t)tid * DD;
        float sv = 0.0f, rl = 0.0f;
        for (int d = 0; d < DD; ++d) { float x = row[d]; sv = fmaf(pw[d], x, sv); rl = fmaf(rW[d], x, rl); }
        sumv[b * RR + tid] = sv;
        r_lin[b * RR + tid] = rl + r_b[0];
    }
}

// ---------------- generic tiled fp32 GEMM: C = A * B^T (+bias1+bias2), exact multiples of 64/16 ----
__global__ __launch_bounds__(256) void k_gemm(
    const float* __restrict__ A, int lda,
    const float* __restrict__ B, int ldb,
    float* __restrict__ C, int ldc, int K,
    const float* __restrict__ bias1, const float* __restrict__ bias2)
{
    __shared__ float As[16][65];
    __shared__ float Bs[16][65];
    int m0 = blockIdx.x * 64, n0 = blockIdx.y * 64;
    int tid = threadIdx.x;
    int tx = tid & 15, ty = tid >> 4;
    int lr = tid >> 2, lc = (tid & 3) * 4;
    float acc[4][4] = {{0.f}};
    for (int k0 = 0; k0 < K; k0 += 16) {
        float4 a4 = *(const float4*)(A + (size_t)(m0 + lr) * lda + k0 + lc);
        float4 b4 = *(const float4*)(B + (size_t)(n0 + lr) * ldb + k0 + lc);
        As[lc + 0][lr] = a4.x; As[lc + 1][lr] = a4.y; As[lc + 2][lr] = a4.z; As[lc + 3][lr] = a4.w;
        Bs[lc + 0][lr] = b4.x; Bs[lc + 1][lr] = b4.y; Bs[lc + 2][lr] = b4.z; Bs[lc + 3][lr] = b4.w;
        __syncthreads();
#pragma unroll
        for (int k = 0; k < 16; ++k) {
            float av[4], bv[4];
#pragma unroll
            for (int i = 0; i < 4; ++i) av[i] = As[k][ty * 4 + i];
#pragma unroll
            for (int j = 0; j < 4; ++j) bv[j] = Bs[k][tx * 4 + j];
#pragma unroll
            for (int i = 0; i < 4; ++i)
#pragma unroll
                for (int j = 0; j < 4; ++j) acc[i][j] = fmaf(av[i], bv[j], acc[i][j]);
        }
        __syncthreads();
    }
#pragma unroll
    for (int i = 0; i < 4; ++i) {
        int m = m0 + ty * 4 + i;
#pragma unroll
        for (int j = 0; j < 4; ++j) {
            int n = n0 + tx * 4 + j;
            float v = acc[i][j];
            if (bias1) v += bias1[n];
            if (bias2) v += bias2[n];
            C[(size_t)m * ldc + n] = v;
        }
    }
}

// ---------------- LSTM cell: gates(K=1536 over [rf|h]) + activations + masked h/c update ----
__global__ __launch_bounds__(256) void k_lstm(
    const float* __restrict__ yT, const float* __restrict__ ge,
    const float* __restrict__ Wih, const float* __restrict__ Whh,
    const int* __restrict__ dec_i,
    float* __restrict__ cT, float* __restrict__ yT_h, int t)
{
    __shared__ float ys[128 * 64];   // 32 KiB K-tile of x^T
    int tid = threadIdx.x;
    int lane = tid & 63;             // b
    int wv = tid >> 6;
    int hp = blockIdx.x * 4 + wv;    // h' in [0,512)
    float ai = 0.f, af = 0.f, ag = 0.f, ao = 0.f;
    const float* geb = ge + (size_t)t * B64 * 2048;
    for (int k0 = 0; k0 < 1536; k0 += 128) {
        const float4* src = (const float4*)(yT + (size_t)k0 * 64);
        float4* dst = (float4*)ys;
#pragma unroll
        for (int i = 0; i < 8; ++i) dst[tid + i * 256] = src[tid + i * 256];
        __syncthreads();
        const float *wi, *wf, *wg, *wo;
        if (k0 < 1024) {
            wi = Wih + (size_t)(hp) * 1280 + 256 + k0;
            wf = Wih + (size_t)(512 + hp) * 1280 + 256 + k0;
            wg = Wih + (size_t)(1024 + hp) * 1280 + 256 + k0;
            wo = Wih + (size_t)(1536 + hp) * 1280 + 256 + k0;
        } else {
            wi = Whh + (size_t)(hp) * 512 + (k0 - 1024);
            wf = Whh + (size_t)(512 + hp) * 512 + (k0 - 1024);
            wg = Whh + (size_t)(1024 + hp) * 512 + (k0 - 1024);
            wo = Whh + (size_t)(1536 + hp) * 512 + (k0 - 1024);
        }
#pragma unroll 4
        for (int kk = 0; kk < 128; kk += 4) {
            float4 w0 = *(const float4*)(wi + kk);
            float4 w1 = *(const float4*)(wf + kk);
            float4 w2 = *(const float4*)(wg + kk);
            float4 w3 = *(const float4*)(wo + kk);
            float y0 = ys[(kk + 0) * 64 + lane];
            float y1 = ys[(kk + 1) * 64 + lane];
            float y2 = ys[(kk + 2) * 64 + lane];
            float y3 = ys[(kk + 3) * 64 + lane];
            ai = fmaf(w0.x, y0, ai); ai = fmaf(w0.y, y1, ai); ai = fmaf(w0.z, y2, ai); ai = fmaf(w0.w, y3, ai);
            af = fmaf(w1.x, y0, af); af = fmaf(w1.y, y1, af); af = fmaf(w1.z, y2, af); af = fmaf(w1.w, y3, af);
            ag = fmaf(w2.x, y0, ag); ag = fmaf(w2.y, y1, ag); ag = fmaf(w2.z, y2, ag); ag = fmaf(w2.w, y3, ag);
            ao = fmaf(w3.x, y0, ao); ao = fmaf(w3.y, y1, ao); ao = fmaf(w3.z, y2, ao); ao = fmaf(w3.w, y3, ao);
        }
        __syncthreads();
    }
    ai += geb[lane * 2048 + hp];
    af += geb[lane * 2048 + 512 + hp];
    ag += geb[lane * 2048 + 1024 + hp];
    ao += geb[lane * 2048 + 1536 + hp];
    float ii = 1.0f / (1.0f + expf(-ai));
    float ff = 1.0f / (1.0f + expf(-af));
    float oo = 1.0f / (1.0f + expf(-ao));
    float gg = tanhf(ag);
    float cold = cT[hp * 64 + lane];
    float cn = ff * cold + ii * gg;
    float hn = oo * tanhf(cn);
    if (dec_i[lane] > t) {
        cT[hp * 64 + lane] = cn;
        yT_h[hp * 64 + lane] = hn;
    }
}

// ---------------- attention + u_t/G/g0 + rf update (block per b) ----------------
__global__ __launch_bounds__(256) void k_attn(
    const float* __restrict__ yT,
    const float* __restrict__ objs_s,
    const float* __restrict__ rh_all,
    const float* __restrict__ sumv, const float* __restrict__ r_lin,
    const float* __restrict__ whW, const float* __restrict__ wh_b,
    const float* __restrict__ wW, const float* __restrict__ w_b,
    const float* __restrict__ emb_sum,
    const float* __restrict__ s_wr, const float* __restrict__ srb,
    const int* __restrict__ dec_i,
    float* __restrict__ yT_rf,
    float* __restrict__ G, float* __restrict__ g0,
    float* __restrict__ attn_out, int t)
{
    int b = blockIdx.x, tid = threadIdx.x;
    __shared__ float hs[HH];
    __shared__ float rvec_s[RR];
    __shared__ float ra_s[RR];
    __shared__ float red1[256], red2[256];
    for (int k = tid; k < HH; k += 256) hs[k] = yT[DD * B64 + k * 64 + b];
    __syncthreads();
    if (tid < RR) {
        const float* rh = rh_all + ((size_t)b * RR + tid) * HH;
        float a = 0.0f;
        for (int k = 0; k < HH; ++k) a = fmaf(rh[k], hs[k], a);
        rvec_s[tid] = a + r_lin[b * RR + tid];
    }
    // u[e] (e = tid)
    float u = 0.0f;
    for (int k = 0; k < HH; ++k) u = fmaf(hs[k], whW[(size_t)k * EE + tid], u);
    float ut = u + wW[tid];
    G[((size_t)t * B64 + b) * EE + tid] = ut + s_wr[b * EE + tid];
    float p1 = 0.0f;
    for (int k = tid; k < HH; k += 256) p1 = fmaf(hs[k], wh_b[k], p1);
    red1[tid] = p1;
    red2[tid] = ut * emb_sum[tid];
    __syncthreads();
    for (int s = 128; s > 0; s >>= 1) {
        if (tid < s) { red1[tid] += red1[tid + s]; red2[tid] += red2[tid + s]; }
        __syncthreads();
    }
    if (tid == 0) {
        float hwb = red1[0] + w_b[0];                 // h.wh_b + w_b
        float wtsum = red2[0] + 12000.0f * hwb;
        float rvs = 0.0f;
        float mx = -3.4e38f;
        for (int r = 0; r < RR; ++r) {
            float rv = rvec_s[r];
            rvs += rv;
            float lg = wtsum + sumv[b * RR + r] + rv;
            red1[r] = lg;                             // reuse as logits
            mx = fmaxf(mx, lg);
        }
        g0[t * B64 + b] = hwb + srb[b] + rvs;
        float ssum = 0.0f;
        for (int r = 0; r < RR; ++r) { float e = expf(red1[r] - mx); ra_s[r] = e; ssum += e; }
        float inv = 1.0f / ssum;
        for (int r = 0; r < RR; ++r) ra_s[r] *= inv;
    }
    __syncthreads();
    bool act = dec_i[b] > t;
    if (tid < RR) attn_out[((size_t)b * TDEC + t) * RR + tid] = act ? ra_s[tid] : 0.0f;
    if (act) {
        for (int d = tid; d < DD; d += 256) {
            float a = 0.0f;
            const float* ob = objs_s + (size_t)b * RR * DD + d;
            for (int r = 0; r < RR; ++r) a = fmaf(ra_s[r], ob[(size_t)r * DD], a);
            yT_rf[d * 64 + b] = a;
        }
    }
}

// ---------------- final predictions GEMM: (20*64 x 256) @ (256 x 12000) + g0, masked ----
__global__ __launch_bounds__(256) void k_preds(
    const float* __restrict__ G, const float* __restrict__ embW,
    const float* __restrict__ g0, const int* __restrict__ dec_i,
    float* __restrict__ out)
{
    __shared__ float As[16][65];
    __shared__ float Bs[16][65];
    int tq = blockIdx.x;            // t
    int n0 = blockIdx.y * 64;
    int tid = threadIdx.x;
    int tx = tid & 15, ty = tid >> 4;
    int lr = tid >> 2, lc = (tid & 3) * 4;
    float acc[4][4] = {{0.f}};
    const float* Ab = G + (size_t)tq * B64 * EE;
    for (int k0 = 0; k0 < EE; k0 += 16) {
        float4 a4 = *(const float4*)(Ab + (size_t)lr * EE + k0 + lc);
        int brow = n0 + lr;
        float4 b4 = make_float4(0.f, 0.f, 0.f, 0.f);
        if (brow < VV) b4 = *(const float4*)(embW + (size_t)brow * EE + k0 + lc);
        As[lc + 0][lr] = a4.x; As[lc + 1][lr] = a4.y; As[lc + 2][lr] = a4.z; As[lc + 3][lr] = a4.w;
        Bs[lc + 0][lr] = b4.x; Bs[lc + 1][lr] = b4.y; Bs[lc + 2][lr] = b4.z; Bs[lc + 3][lr] = b4.w;
        __syncthreads();
#pragma unroll
        for (int k = 0; k < 16; ++k) {
            float av[4], bv[4];
#pragma unroll
            for (int i = 0; i < 4; ++i) av[i] = As[k][ty * 4 + i];
#pragma unroll
            for (int j = 0; j < 4; ++j) bv[j] = Bs[k][tx * 4 + j];
#pragma unroll
            for (int i = 0; i < 4; ++i)
#pragma unroll
                for (int j = 0; j < 4; ++j) acc[i][j] = fmaf(av[i], bv[j], acc[i][j]);
        }
        __syncthreads();
    }
#pragma unroll
    for (int i = 0; i < 4; ++i) {
        int bq = ty * 4 + i;                      // b
        float add = g0[tq * B64 + bq];
        bool act = dec_i[bq] > tq;
        float4 res;
        res.x = act ? acc[i][0] + add : 0.0f;
        res.y = act ? acc[i][1] + add : 0.0f;
        res.z = act ? acc[i][2] + add : 0.0f;
        res.w = act ? acc[i][3] + add : 0.0f;
        int v0 = n0 + tx * 4;
        float* dst = out + ((size_t)bq * TDEC + tq) * VV + v0;
        if (v0 + 3 < VV) {
            *(float4*)dst = res;
        } else {
            if (v0 + 0 < VV) dst[0] = res.x;
            if (v0 + 1 < VV) dst[1] = res.y;
            if (v0 + 2 < VV) dst[2] = res.z;
            if (v0 + 3 < VV) dst[3] = res.w;
        }
    }
}

extern "C" void kernel_launch(void* const* d_in, const int* in_sizes, int n_in,
                              void* d_out, int out_size, void* d_ws, size_t ws_size,
                              hipStream_t stream)
{
    const float* h0      = (const float*)d_in[0];
    const float* objs    = (const float*)d_in[1];
    const int*   caps    = (const int*)d_in[2];
    const int*   cap_len = (const int*)d_in[3];
    const float* embW    = (const float*)d_in[4];
    const float* whW     = (const float*)d_in[5];
    const float* wh_b    = (const float*)d_in[6];
    const float* wrW     = (const float*)d_in[7];
    const float* wr_b    = (const float*)d_in[8];
    const float* rhW     = (const float*)d_in[9];
    const float* rh_b    = (const float*)d_in[10];
    const float* wW      = (const float*)d_in[11];
    const float* w_b     = (const float*)d_in[12];
    const float* rW      = (const float*)d_in[13];
    const float* r_b     = (const float*)d_in[14];
    const float* Wih     = (const float*)d_in[15];
    const float* Whh     = (const float*)d_in[16];
    const float* bih     = (const float*)d_in[17];
    const float* bhh     = (const float*)d_in[18];

    float* out = (float*)d_out;
    float* out_pred = out;                      // 64*20*12000
    float* out_attn = out + 15360000;           // 64*20*36
    float* out_caps = out + 15406080;           // 64*20
    float* out_dec  = out + 15407360;           // 64
    float* out_sind = out + 15407424;           // 64

    float* f = (float*)d_ws;
    size_t o = 0;
    float* objs_s  = f + o; o += (size_t)B64 * RR * DD;    // 2359296
    float* rh_all  = f + o; o += (size_t)B64 * RR * HH;    // 1179648
    float* ge      = f + o; o += (size_t)TDEC * B64 * 2048;// 2621440
    float* Aemb    = f + o; o += (size_t)TDEC * B64 * EE;  // 327680
    float* yT      = f + o; o += (size_t)(DD + HH) * B64;  // 98304
    float* cT      = f + o; o += (size_t)HH * B64;         // 32768
    float* G       = f + o; o += (size_t)TDEC * B64 * EE;  // 327680
    float* g0      = f + o; o += TDEC * B64;               // 1280
    float* embpart = f + o; o += 64 * EE;                  // 16384
    float* emb_sum = f + o; o += EE;
    float* pw      = f + o; o += DD;
    float* sumv    = f + o; o += B64 * RR;
    float* r_lin   = f + o; o += B64 * RR;
    float* s_wr    = f + o; o += B64 * EE;
    float* srb     = f + o; o += B64;
    int* ibase  = (int*)(f + o);
    int* sind   = ibase;
    int* dec_i  = ibase + 64;
    int* caps_s = ibase + 128;                             // 64*21 ints

    k_sort<<<1, 64, 0, stream>>>(cap_len, caps, sind, dec_i, caps_s, out_dec, out_sind, out_caps);
    k_init<<<384, 256, 0, stream>>>(h0, sind, yT, cT);
    k_gobjs<<<2048, 256, 0, stream>>>(objs, sind, objs_s);
    k_gA<<<1280, 256, 0, stream>>>(embW, caps_s, Aemb);
    k_embsum<<<64, 256, 0, stream>>>(embW, embpart);
    k_embred<<<1, 256, 0, stream>>>(embpart, emb_sum);
    k_pwsum<<<4, 256, 0, stream>>>(emb_sum, wrW, wr_b, pw);
    k_objpre<<<64, 256, 0, stream>>>(objs_s, wrW, wr_b, pw, rW, r_b, s_wr, srb, sumv, r_lin);
    {
        dim3 g1(36, 8);
        k_gemm<<<g1, 256, 0, stream>>>(objs_s, DD, rhW, DD, rh_all, HH, DD, rh_b, nullptr);
        dim3 g2(20, 32);
        k_gemm<<<g2, 256, 0, stream>>>(Aemb, EE, Wih, 1280, ge, 2048, EE, bih, bhh);
    }
    for (int t = 0; t < TDEC; ++t) {
        k_lstm<<<128, 256, 0, stream>>>(yT, ge, Wih, Whh, dec_i, cT, yT + DD * B64, t);
        k_attn<<<64, 256, 0, stream>>>(yT, objs_s, rh_all, sumv, r_lin, whW, wh_b, wW, w_b,
                                       emb_sum, s_wr, srb, dec_i, yT, G, g0, out_attn, t);
    }
    {
        dim3 g3(20, 188);
        k_preds<<<g3, 256, 0, stream>>>(G, embW, g0, dec_i, out_pred);
    }
}

// Round 3
// 1084.881 us; speedup vs baseline: 2.5776x; 2.5776x over previous
//
#include <hip/hip_runtime.h>
#include <cstdint>
#include <cstddef>

#define B64 64
#define TDEC 20
#define VV 12000
#define EE 256
#define HH 512
#define DD 1024
#define RR 36

typedef __attribute__((ext_vector_type(8))) short bf16x8;
typedef __attribute__((ext_vector_type(4))) float f32x4;

__device__ __forceinline__ unsigned short f2b(float f) {
    unsigned u = __float_as_uint(f);
    unsigned r = (u + 0x7FFFu + ((u >> 16) & 1u)) >> 16;
    return (unsigned short)r;
}
__device__ __forceinline__ float b2f(unsigned short h) {
    return __uint_as_float(((unsigned)h) << 16);
}

// ---------------- sort (stable argsort desc by length) ----------------
__global__ void k_sort(const int* __restrict__ cap_len,
                       const int* __restrict__ captions,
                       int* __restrict__ sind, int* __restrict__ dec_i,
                       int* __restrict__ caps_s,
                       float* __restrict__ out_dec,
                       float* __restrict__ out_sind,
                       float* __restrict__ out_caps)
{
    int i = threadIdx.x;
    __shared__ int lens[B64];
    lens[i] = cap_len[i];
    __syncthreads();
    int li = lens[i];
    int rank = 0;
    for (int j = 0; j < B64; ++j) {
        int lj = lens[j];
        if (lj > li || (lj == li && j < i)) rank++;
    }
    sind[rank] = i;
    dec_i[rank] = li - 1;
    out_dec[rank] = (float)(li - 1);
    out_sind[rank] = (float)i;
    for (int t = 0; t < 21; ++t) {
        int tok = captions[i * 21 + t];
        caps_s[rank * 21 + t] = tok;
        if (t >= 1) out_caps[rank * 20 + (t - 1)] = (float)tok;
    }
}

// ---------------- init xN[0] (rf=0 | h0 bf16) and cT fp32 ----------------
__global__ void k_init(const float* __restrict__ h0, const int* __restrict__ sind,
                       unsigned short* __restrict__ xN0, float* __restrict__ cT)
{
    int idx = blockIdx.x * blockDim.x + threadIdx.x;
    const int totX = B64 * 1536;
    if (idx < totX) {
        int b = idx / 1536, k = idx - b * 1536;
        unsigned short v = 0;
        if (k >= 1024) v = f2b(h0[sind[b] * HH + (k - 1024)]);
        xN0[idx] = v;
    } else {
        int j = idx - totX;           // hp*64+b
        if (j < HH * B64) {
            int hp = j >> 6, b = j & 63;
            cT[j] = h0[sind[b] * HH + hp];
        }
    }
}

// ---------------- gather sorted object proposals -> bf16 ----------------
__global__ void k_gobjs(const float* __restrict__ objs, const int* __restrict__ sind,
                        unsigned short* __restrict__ objs_b)
{
    size_t idx = (size_t)blockIdx.x * blockDim.x + threadIdx.x;
    const size_t total = (size_t)B64 * RR * DD;
    const size_t stride = (size_t)gridDim.x * blockDim.x;
    for (; idx < total; idx += stride) {
        int b = (int)(idx / (RR * DD));
        int rest = (int)(idx % (RR * DD));
        objs_b[idx] = f2b(objs[(size_t)sind[b] * (RR * DD) + rest]);
    }
}

// ---------------- gather embeddings for all (t,b) -> bf16 ----------------
__global__ void k_gA(const float* __restrict__ embW, const int* __restrict__ caps_s,
                     unsigned short* __restrict__ AembB)
{
    int idx = blockIdx.x * blockDim.x + threadIdx.x;
    if (idx >= TDEC * B64 * EE) return;
    int tb = idx >> 8, e = idx & 255;
    int t = tb >> 6, b = tb & 63;
    int tok = caps_s[b * 21 + t];
    AembB[idx] = f2b(embW[(size_t)tok * EE + e]);
}

// ---------------- generic fp32->bf16 2D convert (row-major, ld >= cols) ----
__global__ void k_cvt2d(const float* __restrict__ src, int ld, int cols,
                        unsigned short* __restrict__ dst, int total)
{
    int idx = blockIdx.x * blockDim.x + threadIdx.x;
    if (idx >= total) return;
    int row = idx / cols, col = idx - row * cols;
    dst[idx] = f2b(src[(size_t)row * ld + col]);
}

// ---------------- whT[e][k] = bf16(whW[k][e]) ----------------
__global__ void k_mkwht(const float* __restrict__ whW, unsigned short* __restrict__ whT)
{
    int idx = blockIdx.x * blockDim.x + threadIdx.x;
    if (idx >= EE * HH) return;
    int e = idx >> 9, k = idx & 511;
    whT[idx] = f2b(whW[(size_t)k * EE + e]);
}

// ---------------- Wc[m=hp*4+g][1536] = [Wih(:,256:1280) | Whh] bf16 ----------
__global__ void k_mkwc(const float* __restrict__ Wih, const float* __restrict__ Whh,
                       unsigned short* __restrict__ Wc)
{
    int idx = blockIdx.x * blockDim.x + threadIdx.x;
    if (idx >= 2048 * 1536) return;
    int m = idx / 1536, k = idx - m * 1536;
    int hp = m >> 2, g = m & 3;
    int ro = g * 512 + hp;
    float v = (k < 1024) ? Wih[(size_t)ro * 1280 + 256 + k]
                         : Whh[(size_t)ro * 512 + (k - 1024)];
    Wc[idx] = f2b(v);
}

// ---------------- emb_sum partials + reduce (fp32 exact) ----------------
__global__ void k_embsum(const float* __restrict__ embW, float* __restrict__ partial)
{
    int e = threadIdx.x;
    int v0 = blockIdx.x * 188;
    int v1 = v0 + 188; if (v1 > VV) v1 = VV;
    float a = 0.0f;
    for (int v = v0; v < v1; ++v) a += embW[(size_t)v * EE + e];
    partial[blockIdx.x * EE + e] = a;
}
__global__ void k_embred(const float* __restrict__ partial, float* __restrict__ emb_sum)
{
    int e = threadIdx.x;
    float a = 0.0f;
    for (int j = 0; j < 64; ++j) a += partial[j * EE + e];
    emb_sum[e] = a;
}

// ---------------- pw[d] = emb_sum . wr_W[d,:] + V*wr_b[d] ----------------
__global__ void k_pwsum(const float* __restrict__ emb_sum, const float* __restrict__ wrW,
                        const float* __restrict__ wr_b, float* __restrict__ pw)
{
    __shared__ float es[EE];
    es[threadIdx.x] = emb_sum[threadIdx.x];
    __syncthreads();
    int d = blockIdx.x * 256 + threadIdx.x;
    float a = 0.0f;
    const float* row = wrW + (size_t)d * EE;
    for (int e = 0; e < EE; ++e) a = fmaf(es[e], row[e], a);
    pw[d] = a + 12000.0f * wr_b[d];
}

// ---------------- per-b: obj_sum -> s_wr, srb, sumv_wr, r_lin (bf16 objs) ----
__global__ void k_objpre(const unsigned short* __restrict__ objs_b, const float* __restrict__ wrW,
                         const float* __restrict__ wr_b, const float* __restrict__ pw,
                         const float* __restrict__ rW, const float* __restrict__ r_b,
                         float* __restrict__ s_wr, float* __restrict__ srb,
                         float* __restrict__ sumv, float* __restrict__ r_lin)
{
    int b = blockIdx.x, tid = threadIdx.x;
    __shared__ float os[DD];
    __shared__ float red[256];
    const unsigned short* ob = objs_b + (size_t)b * RR * DD;
    for (int d = tid; d < DD; d += 256) {
        float a = 0.0f;
        for (int r = 0; r < RR; ++r) a += b2f(ob[r * DD + d]);
        os[d] = a;
    }
    __syncthreads();
    float a = 0.0f;
    for (int d = 0; d < DD; ++d) a = fmaf(os[d], wrW[(size_t)d * EE + tid], a);
    s_wr[b * EE + tid] = a;
    float p = 0.0f;
    for (int d = tid; d < DD; d += 256) p = fmaf(os[d], wr_b[d], p);
    red[tid] = p;
    __syncthreads();
    for (int s = 128; s > 0; s >>= 1) { if (tid < s) red[tid] += red[tid + s]; __syncthreads(); }
    if (tid == 0) srb[b] = red[0];
    if (tid < RR) {
        const unsigned short* row = ob + (size_t)tid * DD;
        float sv = 0.0f, rl = 0.0f;
        for (int d = 0; d < DD; ++d) { float x = b2f(row[d]); sv = fmaf(pw[d], x, sv); rl = fmaf(rW[d], x, rl); }
        sumv[b * RR + tid] = sv;
        r_lin[b * RR + tid] = rl + r_b[0];
    }
}

// ---------------- generic bf16 MFMA GEMM: C = A*B^T + bias1 + bias2 ----------
// A[M][lda] bf16, B[N][ldb] bf16, C fp32 [M][ldc]. M%32==0, N%32==0, K%64==0.
__global__ __launch_bounds__(256) void k_bgemm(
    const unsigned short* __restrict__ A, int lda,
    const unsigned short* __restrict__ B, int ldb,
    float* __restrict__ C, int ldc, int K,
    const float* __restrict__ bias1, const float* __restrict__ bias2)
{
    int tid = threadIdx.x;
    int wv = tid >> 6, lane = tid & 63;
    int l15 = lane & 15, lg = lane >> 4;
    int m0 = blockIdx.x * 32 + (wv & 1) * 16;
    int n0 = blockIdx.y * 32 + (wv >> 1) * 16;
    const unsigned short* Ar = A + (size_t)(m0 + l15) * lda + lg * 8;
    const unsigned short* Br = B + (size_t)(n0 + l15) * ldb + lg * 8;
    f32x4 acc0 = {0.f, 0.f, 0.f, 0.f}, acc1 = {0.f, 0.f, 0.f, 0.f};
#pragma unroll 4
    for (int k0 = 0; k0 < K; k0 += 64) {
        bf16x8 a0 = *(const bf16x8*)(Ar + k0);
        bf16x8 b0 = *(const bf16x8*)(Br + k0);
        bf16x8 a1 = *(const bf16x8*)(Ar + k0 + 32);
        bf16x8 b1 = *(const bf16x8*)(Br + k0 + 32);
        acc0 = __builtin_amdgcn_mfma_f32_16x16x32_bf16(a0, b0, acc0, 0, 0, 0);
        acc1 = __builtin_amdgcn_mfma_f32_16x16x32_bf16(a1, b1, acc1, 0, 0, 0);
    }
    int n = n0 + l15;
    float badd = 0.0f;
    if (bias1) badd += bias1[n];
    if (bias2) badd += bias2[n];
#pragma unroll
    for (int r = 0; r < 4; ++r) {
        int m = m0 + 4 * lg + r;
        C[(size_t)m * ldc + n] = acc0[r] + acc1[r] + badd;
    }
}

// ---------------- LSTM step: gates via MFMA + activations + masked h/c ----------
// Wc rows m=hp*4+gate -> each lane holds i,f,g,o of one (hp,b) in its 4 acc regs.
__global__ __launch_bounds__(256) void k_step1(
    const unsigned short* __restrict__ Wc,
    const unsigned short* __restrict__ xin,   // [64][1536] bf16 (rf|h)
    unsigned short* __restrict__ xout,        // h rows written here
    const float* __restrict__ ge,             // [1280][2048] fp32 (incl. biases)
    float* __restrict__ cT,                   // [512][64] fp32
    const int* __restrict__ dec_i, int t)
{
    int tid = threadIdx.x;
    int wv = tid >> 6, lane = tid & 63;
    int l15 = lane & 15, lg = lane >> 4;
    int m0 = blockIdx.x * 16;
    int n0 = wv * 16;
    int hp = blockIdx.x * 4 + lg;
    int b  = n0 + l15;
    // prefetch scalars early
    int dec = dec_i[b];
    const float* geb = ge + ((size_t)t * 64 + b) * 2048;
    float ge0 = geb[hp], ge1 = geb[512 + hp], ge2 = geb[1024 + hp], ge3 = geb[1536 + hp];
    float cold = cT[hp * 64 + b];
    unsigned short hold = xin[(size_t)b * 1536 + 1024 + hp];

    const unsigned short* Ar = Wc + (size_t)(m0 + l15) * 1536 + lg * 8;
    const unsigned short* Br = xin + (size_t)(n0 + l15) * 1536 + lg * 8;
    f32x4 acc0 = {0.f, 0.f, 0.f, 0.f}, acc1 = {0.f, 0.f, 0.f, 0.f};
#pragma unroll 6
    for (int k0 = 0; k0 < 1536; k0 += 64) {
        bf16x8 a0 = *(const bf16x8*)(Ar + k0);
        bf16x8 b0 = *(const bf16x8*)(Br + k0);
        bf16x8 a1 = *(const bf16x8*)(Ar + k0 + 32);
        bf16x8 b1 = *(const bf16x8*)(Br + k0 + 32);
        acc0 = __builtin_amdgcn_mfma_f32_16x16x32_bf16(a0, b0, acc0, 0, 0, 0);
        acc1 = __builtin_amdgcn_mfma_f32_16x16x32_bf16(a1, b1, acc1, 0, 0, 0);
    }
    float gi = acc0[0] + acc1[0] + ge0;
    float gf = acc0[1] + acc1[1] + ge1;
    float gg = acc0[2] + acc1[2] + ge2;
    float go = acc0[3] + acc1[3] + ge3;
    float ii = 1.0f / (1.0f + expf(-gi));
    float ff = 1.0f / (1.0f + expf(-gf));
    float oo = 1.0f / (1.0f + expf(-go));
    float g2 = tanhf(gg);
    float cn = ff * cold + ii * g2;
    float hn = oo * tanhf(cn);
    bool act = dec > t;
    if (act) cT[hp * 64 + b] = cn;
    xout[(size_t)b * 1536 + 1024 + hp] = act ? f2b(hn) : hold;
}

// ---------------- attention + u_t/G/g0 + rf (block per b) ----------------
__global__ __launch_bounds__(256) void k_step2(
    const unsigned short* __restrict__ xh,    // h source: [64][1536], rows 1024..1535
    const unsigned short* __restrict__ xin,   // old rf source (rows 0..1023)
    const unsigned short* __restrict__ objs_b,
    const float* __restrict__ rh_all,         // [64*36][512]
    const float* __restrict__ sumv, const float* __restrict__ r_lin,
    const unsigned short* __restrict__ whT,   // [256][512] bf16
    const float* __restrict__ wh_b, const float* __restrict__ wW, const float* __restrict__ w_b,
    const float* __restrict__ emb_sum,
    const float* __restrict__ s_wr, const float* __restrict__ srb,
    const int* __restrict__ dec_i,
    unsigned short* __restrict__ Gb, float* __restrict__ g0,
    float* __restrict__ attn_out, int t)
{
    int b = blockIdx.x, tid = threadIdx.x;
    __shared__ float hs[HH];
    __shared__ float rpart[RR][4];
    __shared__ float rvec_s[RR];
    __shared__ float ra_s[RR];
    __shared__ float lg_s[RR];
    __shared__ float red1[256], red2[256];
    // load h (bf16 pairs -> fp32)
    {
        unsigned v = *(const unsigned*)(xh + (size_t)b * 1536 + 1024 + tid * 2);
        hs[tid * 2]     = __uint_as_float((v & 0xFFFFu) << 16);
        hs[tid * 2 + 1] = __uint_as_float(v & 0xFFFF0000u);
    }
    __syncthreads();
    // rvec partials: 4 threads per r
    if (tid < RR * 4) {
        int r = tid >> 2, q = tid & 3;
        const float* rh = rh_all + ((size_t)b * RR + r) * HH + q * 128;
        float a = 0.0f;
        const float* hq = hs + q * 128;
#pragma unroll 4
        for (int k = 0; k < 128; ++k) a = fmaf(rh[k], hq[k], a);
        rpart[r][q] = a;
    }
    // u[e], e = tid
    float u = 0.0f;
    {
        const unsigned short* wr = whT + (size_t)tid * HH;
#pragma unroll 2
        for (int i = 0; i < 64; ++i) {
            bf16x8 w8 = *(const bf16x8*)(wr + i * 8);
#pragma unroll
            for (int j = 0; j < 8; ++j)
                u = fmaf(__uint_as_float(((unsigned)(unsigned short)w8[j]) << 16), hs[i * 8 + j], u);
        }
    }
    float ut = u + wW[tid];
    float swr = s_wr[b * EE + tid];
    Gb[((size_t)t * B64 + b) * EE + tid] = f2b(ut + swr);
    float p1 = 0.0f;
    p1 = fmaf(hs[tid], wh_b[tid], p1);
    p1 = fmaf(hs[tid + 256], wh_b[tid + 256], p1);
    red1[tid] = p1;
    red2[tid] = ut * emb_sum[tid];
    __syncthreads();
    if (tid < RR) rvec_s[tid] = rpart[tid][0] + rpart[tid][1] + rpart[tid][2] + rpart[tid][3]
                                + r_lin[b * RR + tid];
    for (int s = 128; s > 0; s >>= 1) {
        if (tid < s) { red1[tid] += red1[tid + s]; red2[tid] += red2[tid + s]; }
        __syncthreads();
    }
    if (tid == 0) {
        float hwb = red1[0] + w_b[0];
        float wtsum = red2[0] + 12000.0f * hwb;
        float rvs = 0.0f, mx = -3.4e38f;
        for (int r = 0; r < RR; ++r) {
            float rv = rvec_s[r];
            rvs += rv;
            float lg = wtsum + sumv[b * RR + r] + rv;
            lg_s[r] = lg;
            mx = fmaxf(mx, lg);
        }
        g0[t * B64 + b] = hwb + srb[b] + rvs;
        float ssum = 0.0f;
        for (int r = 0; r < RR; ++r) { float e = expf(lg_s[r] - mx); ra_s[r] = e; ssum += e; }
        float inv = 1.0f / ssum;
        for (int r = 0; r < RR; ++r) ra_s[r] *= inv;
    }
    __syncthreads();
    bool act = dec_i[b] > t;
    if (tid < RR) attn_out[((size_t)b * TDEC + t) * RR + tid] = act ? ra_s[tid] : 0.0f;
    // rf update (or copy-forward) into xh rf rows
    {
        int d0 = tid * 4;
        unsigned short* dst = (unsigned short*)(xh + (size_t)b * 1536 + d0);
        if (act) {
            float a0 = 0.f, a1 = 0.f, a2 = 0.f, a3 = 0.f;
            const unsigned short* ob = objs_b + (size_t)b * RR * DD + d0;
#pragma unroll 4
            for (int r = 0; r < RR; ++r) {
                ushort4 o4 = *(const ushort4*)(ob + (size_t)r * DD);
                a0 = fmaf(ra_s[r], b2f(o4.x), a0);
                a1 = fmaf(ra_s[r], b2f(o4.y), a1);
                a2 = fmaf(ra_s[r], b2f(o4.z), a2);
                a3 = fmaf(ra_s[r], b2f(o4.w), a3);
            }
            ushort4 w4; w4.x = f2b(a0); w4.y = f2b(a1); w4.z = f2b(a2); w4.w = f2b(a3);
            *(ushort4*)dst = w4;
        } else {
            *(ushort4*)dst = *(const ushort4*)(xin + (size_t)b * 1536 + d0);
        }
    }
}

// ---------------- final predictions: (1280x256)@(256x12000) MFMA + g0 + mask ----
__global__ __launch_bounds__(256) void k_preds(
    const unsigned short* __restrict__ Gb, const unsigned short* __restrict__ embB,
    const float* __restrict__ g0, const int* __restrict__ dec_i,
    float* __restrict__ out)
{
    int tid = threadIdx.x;
    int wv = tid >> 6, lane = tid & 63;
    int l15 = lane & 15, lg = lane >> 4;
    int tq = blockIdx.x;
    int n00 = blockIdx.y * 128;
    int m0 = tq * 64 + wv * 16;
    bf16x8 afr[8];
    const unsigned short* Ar = Gb + (size_t)(m0 + l15) * EE + lg * 8;
#pragma unroll
    for (int k = 0; k < 8; ++k) afr[k] = *(const bf16x8*)(Ar + k * 32);
    float add[4]; bool act[4]; int brow[4];
#pragma unroll
    for (int r = 0; r < 4; ++r) {
        int bb = wv * 16 + 4 * lg + r;
        brow[r] = bb;
        add[r] = g0[tq * 64 + bb];
        act[r] = dec_i[bb] > tq;
    }
    const bf16x8 zb = {0, 0, 0, 0, 0, 0, 0, 0};
#pragma unroll
    for (int nf = 0; nf < 8; ++nf) {
        int nb = n00 + nf * 16 + l15;
        bool bok = nb < VV;
        const unsigned short* Br = embB + (size_t)nb * EE + lg * 8;
        f32x4 acc = {0.f, 0.f, 0.f, 0.f};
#pragma unroll
        for (int k = 0; k < 8; ++k) {
            bf16x8 bb8 = bok ? *(const bf16x8*)(Br + k * 32) : zb;
            acc = __builtin_amdgcn_mfma_f32_16x16x32_bf16(afr[k], bb8, acc, 0, 0, 0);
        }
        if (bok) {
#pragma unroll
            for (int r = 0; r < 4; ++r) {
                float v = act[r] ? acc[r] + add[r] : 0.0f;
                out[((size_t)brow[r] * TDEC + tq) * VV + nb] = v;
            }
        }
    }
}

extern "C" void kernel_launch(void* const* d_in, const int* in_sizes, int n_in,
                              void* d_out, int out_size, void* d_ws, size_t ws_size,
                              hipStream_t stream)
{
    const float* h0      = (const float*)d_in[0];
    const float* objs    = (const float*)d_in[1];
    const int*   caps    = (const int*)d_in[2];
    const int*   cap_len = (const int*)d_in[3];
    const float* embW    = (const float*)d_in[4];
    const float* whW     = (const float*)d_in[5];
    const float* wh_b    = (const float*)d_in[6];
    const float* wrW     = (const float*)d_in[7];
    const float* wr_b    = (const float*)d_in[8];
    const float* rhW     = (const float*)d_in[9];
    const float* rh_b    = (const float*)d_in[10];
    const float* wW      = (const float*)d_in[11];
    const float* w_b     = (const float*)d_in[12];
    const float* rW      = (const float*)d_in[13];
    const float* r_b     = (const float*)d_in[14];
    const float* Wih     = (const float*)d_in[15];
    const float* Whh     = (const float*)d_in[16];
    const float* bih     = (const float*)d_in[17];
    const float* bhh     = (const float*)d_in[18];

    float* out = (float*)d_out;
    float* out_pred = out;                      // 64*20*12000
    float* out_attn = out + 15360000;           // 64*20*36
    float* out_caps = out + 15406080;           // 64*20
    float* out_dec  = out + 15407360;           // 64
    float* out_sind = out + 15407424;           // 64

    // ---- workspace layout (fp32 region first, then bf16/ushort, then ints) ----
    float* f = (float*)d_ws;
    size_t o = 0;
    float* rh_all  = f + o; o += (size_t)B64 * RR * HH;    // 1,179,648
    float* ge      = f + o; o += (size_t)TDEC * B64 * 2048;// 2,621,440
    float* cT      = f + o; o += (size_t)HH * B64;         // 32,768
    float* g0      = f + o; o += TDEC * B64;               // 1,280
    float* embpart = f + o; o += 64 * EE;                  // 16,384
    float* emb_sum = f + o; o += EE;
    float* pw      = f + o; o += DD;
    float* sumv    = f + o; o += B64 * RR;                 // 2,304
    float* r_lin   = f + o; o += B64 * RR;
    float* s_wr    = f + o; o += B64 * EE;                 // 16,384
    float* srb     = f + o; o += B64;
    o = (o + 3) & ~(size_t)3;                              // 16B align
    unsigned short* us = (unsigned short*)(f + o);
    size_t uo = 0;
    unsigned short* xN0    = us + uo; uo += (size_t)B64 * 1536;     // 98,304
    unsigned short* xN1    = us + uo; uo += (size_t)B64 * 1536;
    unsigned short* objs_b = us + uo; uo += (size_t)B64 * RR * DD;  // 2,359,296
    unsigned short* AembB  = us + uo; uo += (size_t)TDEC * B64 * EE;// 327,680
    unsigned short* rhW_b  = us + uo; uo += (size_t)HH * DD;        // 524,288
    unsigned short* embB   = us + uo; uo += (size_t)VV * EE;        // 3,072,000
    unsigned short* WihB   = us + uo; uo += (size_t)2048 * EE;      // 524,288
    unsigned short* whT    = us + uo; uo += (size_t)EE * HH;        // 131,072
    unsigned short* Wc     = us + uo; uo += (size_t)2048 * 1536;    // 3,145,728
    unsigned short* Gb     = us + uo; uo += (size_t)TDEC * B64 * EE;// 327,680
    int* ibase  = (int*)(us + uo);
    int* sind   = ibase;
    int* dec_i  = ibase + 64;
    int* caps_s = ibase + 128;                                      // 64*21

    k_sort<<<1, 64, 0, stream>>>(cap_len, caps, sind, dec_i, caps_s, out_dec, out_sind, out_caps);
    k_init<<<512, 256, 0, stream>>>(h0, sind, xN0, cT);
    k_gobjs<<<1024, 256, 0, stream>>>(objs, sind, objs_b);
    k_gA<<<1280, 256, 0, stream>>>(embW, caps_s, AembB);
    k_embsum<<<64, 256, 0, stream>>>(embW, embpart);
    k_embred<<<1, 256, 0, stream>>>(embpart, emb_sum);
    k_pwsum<<<4, 256, 0, stream>>>(emb_sum, wrW, wr_b, pw);
    k_objpre<<<64, 256, 0, stream>>>(objs_b, wrW, wr_b, pw, rW, r_b, s_wr, srb, sumv, r_lin);
    // conversions
    k_cvt2d<<<2048, 256, 0, stream>>>(rhW, DD, DD, rhW_b, HH * DD);
    k_cvt2d<<<12000, 256, 0, stream>>>(embW, EE, EE, embB, VV * EE);
    k_cvt2d<<<2048, 256, 0, stream>>>(Wih, 1280, EE, WihB, 2048 * EE);
    k_mkwht<<<512, 256, 0, stream>>>(whW, whT);
    k_mkwc<<<12288, 256, 0, stream>>>(Wih, Whh, Wc);
    // pre-GEMMs (bf16 MFMA)
    {
        dim3 g1(72, 16);   // rh_all: M=2304, N=512, K=1024
        k_bgemm<<<g1, 256, 0, stream>>>(objs_b, DD, rhW_b, DD, rh_all, HH, DD, rh_b, nullptr);
        dim3 g2(40, 64);   // ge: M=1280, N=2048, K=256
        k_bgemm<<<g2, 256, 0, stream>>>(AembB, EE, WihB, EE, ge, 2048, EE, bih, bhh);
    }
    // recurrence
    for (int t = 0; t < TDEC; ++t) {
        unsigned short* xin  = (t & 1) ? xN1 : xN0;
        unsigned short* xout = (t & 1) ? xN0 : xN1;
        k_step1<<<128, 256, 0, stream>>>(Wc, xin, xout, ge, cT, dec_i, t);
        k_step2<<<64, 256, 0, stream>>>(xout, xin, objs_b, rh_all, sumv, r_lin, whT,
                                        wh_b, wW, w_b, emb_sum, s_wr, srb, dec_i,
                                        Gb, g0, out_attn, t);
    }
    {
        dim3 g3(20, 94);
        k_preds<<<g3, 256, 0, stream>>>(Gb, embB, g0, dec_i, out_pred);
    }
}